// Round 6
// baseline (206.199 us; speedup 1.0000x reference)
//
#include <hip/hip_runtime.h>

// Problem constants (match reference file)
constexpr int B = 32768;
constexpr int D = 1024;
constexpr int S = 64;
constexpr int O = 4;

// ---------------------------------------------------------------------------
// R6 = R5 (W transposed in LDS, ballot-compaction, 12-shuffle reduce) with
// the three deltas the R5 post-mortem motivated:
//
//  1. amdgpu_waves_per_eu(4,4): R4 proved __launch_bounds__(256,4) does NOT
//     stop the allocator from picking 64 VGPRs and spilling (it is only a
//     MIN).  Pinning max=4 waves/EU gives a 128-VGPR budget -> no spill for
//     this ~85-reg loop.  16 waves/CU still covers the x-stream latency
//     (need ~10KB in flight per CU, steady state has ~64KB).
//  2. Prefetch-BEFORE-compute (R4's proven named-A/B loop shape): next row's
//     x loads issue ~600cy before consumption instead of ~350 (R5 issued
//     them after the FMA block).
//  3. CHUNKS 32->16: 1024 blocks x 4 waves, ~8 rows/wave.  Halves prologue
//     executions and W LDS-staging traffic, doubles steady-state run length.
//     LDS = 16KB Wt + 8KB list = 24KB; grid exactly co-resident (4 blk/CU).
// ---------------------------------------------------------------------------

constexpr int CHUNKS      = 16;             // chunks per subject
constexpr int CHUNK       = B / CHUNKS;     // 2048 rows per block
constexpr int SEG         = CHUNK / 4;      // 512 rows per wave
constexpr int MAIN_BLOCKS = S * CHUNKS;     // 1024 blocks

__global__ __launch_bounds__(256)
__attribute__((amdgpu_waves_per_eu(4, 4)))
void main_kernel(
    const float* __restrict__ x,      // [B, D]
    const int*   __restrict__ sid,    // [B]
    const float* __restrict__ W,      // [S, D, O]
    const float* __restrict__ bias,   // [S, O]
    float*       __restrict__ out)    // [B, O]
{
    __shared__ float Wt[O * D];               // 16 KB: plane o at Wt[o*1024 + d]
    __shared__ int   list[4][SEG];            // 8 KB: per-wave match lists

    const int t    = threadIdx.x;
    const int lane = t & 63;
    const int wave = t >> 6;
    const int s    = blockIdx.x >> 4;         // 16 consecutive blocks share s
    const int c    = blockIdx.x & 15;
    const int q    = lane >> 4;               // output index this lane stores

    // ---- 1. Stage W[s]^T into LDS (coalesced float4 reads; scalar writes
    //         bank = d%32 = t%32, 2 lanes/bank = free). ----
    {
        const float4* Wp = (const float4*)(W + (size_t)s * (D * O));
        #pragma unroll
        for (int r = 0; r < 4; ++r) {
            const int d = r * 256 + t;
            const float4 w4 = Wp[d];          // W[s][d][0..3]
            Wt[0 * D + d] = w4.x;
            Wt[1 * D + d] = w4.y;
            Wt[2 * D + d] = w4.z;
            Wt[3 * D + d] = w4.w;
        }
    }

    // ---- 2. Scan my 512-row sid segment, ballot-compact matches into the
    //         wave-private list (R4/R5-proven). ----
    const int seg = c * CHUNK + wave * SEG;
    int cnt = 0;
    #pragma unroll
    for (int r = 0; r < 8; ++r) {
        const int i = seg + r * 64 + lane;                 // coalesced 256B
        const bool m = (sid[i] == s);
        const unsigned long long mask = __ballot(m);
        const int rank = __popcll(mask & ((1ull << lane) - 1ull));
        if (m) list[wave][cnt + rank] = i;
        cnt += __popcll(mask);                             // lane-uniform
    }

    __syncthreads();                          // Wt visible to all waves
    if (cnt == 0) return;

    const float   bb  = bias[(s << 2) + q];
    const float4* Wt4 = (const float4*)Wt;    // plane o at float4 index o*256

#define LOADX(XB, ROW)                                                         \
    {                                                                          \
        const float4* xr = (const float4*)(x + ((size_t)(ROW) << 10));         \
        _Pragma("unroll")                                                      \
        for (int j = 0; j < 4; ++j) XB[j] = xr[64 * j + lane];                 \
    }

#define COMPUTE(XC, ROW)                                                       \
    {                                                                          \
        float a0 = 0.f, a1 = 0.f, a2 = 0.f, a3 = 0.f;                          \
        _Pragma("unroll")                                                      \
        for (int j = 0; j < 4; ++j) {                                          \
            const float4 xv = XC[j];                                           \
            const float4 w0 = Wt4[0 * 256 + 64 * j + lane];                    \
            const float4 w1 = Wt4[1 * 256 + 64 * j + lane];                    \
            const float4 w2 = Wt4[2 * 256 + 64 * j + lane];                    \
            const float4 w3 = Wt4[3 * 256 + 64 * j + lane];                    \
            a0 += xv.x * w0.x; a1 += xv.x * w1.x;                              \
            a2 += xv.x * w2.x; a3 += xv.x * w3.x;                              \
            a0 += xv.y * w0.y; a1 += xv.y * w1.y;                              \
            a2 += xv.y * w2.y; a3 += xv.y * w3.y;                              \
            a0 += xv.z * w0.z; a1 += xv.z * w1.z;                              \
            a2 += xv.z * w2.z; a3 += xv.z * w3.z;                              \
            a0 += xv.w * w0.w; a1 += xv.w * w1.w;                              \
            a2 += xv.w * w2.w; a3 += xv.w * w3.w;                              \
        }                                                                      \
        _Pragma("unroll")                                                      \
        for (int m = 16; m <= 32; m <<= 1) {                                   \
            a0 += __shfl_xor(a0, m, 64);                                       \
            a1 += __shfl_xor(a1, m, 64);                                       \
            a2 += __shfl_xor(a2, m, 64);                                       \
            a3 += __shfl_xor(a3, m, 64);                                       \
        }                                                                      \
        float v = (q == 0) ? a0 : (q == 1) ? a1 : (q == 2) ? a2 : a3;          \
        _Pragma("unroll")                                                      \
        for (int m = 1; m <= 8; m <<= 1)                                       \
            v += __shfl_xor(v, m, 64);                                         \
        if ((lane & 15) == 0)                 /* lanes 0,16,32,48 -> o=0..3 */ \
            out[((size_t)(ROW) << 2) + q] = v + bb;                            \
    }

    // ---- 3. Stream matched rows; prefetch issues BEFORE current compute
    //         (named A/B buffers, all register indices literal). ----
    float4 xbA[4], xbB[4];
    int rowA = __builtin_amdgcn_readfirstlane(list[wave][0]);
    LOADX(xbA, rowA)

    int k = 0;
    #pragma unroll 1
    while (k + 2 <= cnt) {
        const int rowB = __builtin_amdgcn_readfirstlane(list[wave][k + 1]);
        LOADX(xbB, rowB)
        COMPUTE(xbA, rowA)
        if (k + 2 < cnt) {
            const int rowN = __builtin_amdgcn_readfirstlane(list[wave][k + 2]);
            LOADX(xbA, rowN)
            COMPUTE(xbB, rowB)
            rowA = rowN;
        } else {
            COMPUTE(xbB, rowB)
        }
        k += 2;
    }
    if (k < cnt)                      // odd tail: xbA holds list[k]
        COMPUTE(xbA, rowA)

#undef LOADX
#undef COMPUTE
}

extern "C" void kernel_launch(void* const* d_in, const int* in_sizes, int n_in,
                              void* d_out, int out_size, void* d_ws, size_t ws_size,
                              hipStream_t stream) {
    const float* x    = (const float*)d_in[0];   // [B, D]
    const int*   sid  = (const int*)d_in[1];     // [B]
    const float* W    = (const float*)d_in[2];   // [S, D, O]
    const float* bias = (const float*)d_in[3];   // [S, O]
    float* out = (float*)d_out;                  // [B, O]

    main_kernel<<<MAIN_BLOCKS, 256, 0, stream>>>(x, sid, W, bias, out);
}

// Round 7
// 202.564 us; speedup vs baseline: 1.0179x; 1.0179x over previous
//
#include <hip/hip_runtime.h>

// Problem constants (match reference file)
constexpr int B = 32768;
constexpr int D = 1024;
constexpr int S = 64;
constexpr int O = 4;

// ---------------------------------------------------------------------------
// R7 = R5 (best: 200.5us; W^T in LDS, ballot-compaction, 12-shuffle reduce,
// single-xb 64-reg steady loop at 32 waves/CU) with the prologue halved and
// overlapped.  R6 taught us: waves_per_eu(4,4) (16 waves/CU) is a net loss ->
// reverted; stay at <=64 VGPR so the default 8-waves/EU allocation holds.
//
// Deltas vs R5:
//  1. 1024 blocks x 512 threads (8 waves) instead of 2048 x 256: same
//     32 waves/CU (4 blocks/CU, grid exactly co-resident), but W-staging
//     traffic halves (32MB -> 16MB of L2 reads) and sid-scan traffic halves
//     (16MB -> 8MB).  Fewer, wider prologues.
//  2. list entries are ushort (rows < 32768): LDS = 16KB Wt + 4KB list
//     = 20480B, so LDS is not the occupancy limiter (threads are).
//  3. Each wave issues its FIRST x-row prefetch + bias load BEFORE
//     __syncthreads (list is wave-private, xb is registers): the x stream
//     starts under the W-stage instead of strictly after it.
//  4. sid scan placed before W staging so ballot VALU work overlaps the
//     W global loads.
// ---------------------------------------------------------------------------

constexpr int CHUNKS      = 16;             // chunks per subject
constexpr int CHUNK       = B / CHUNKS;     // 2048 rows per block
constexpr int WAVES       = 8;              // 512 threads
constexpr int SEG         = CHUNK / WAVES;  // 256 rows per wave
constexpr int MAIN_BLOCKS = S * CHUNKS;     // 1024 blocks

__global__ __launch_bounds__(512) void main_kernel(
    const float* __restrict__ x,      // [B, D]
    const int*   __restrict__ sid,    // [B]
    const float* __restrict__ W,      // [S, D, O]
    const float* __restrict__ bias,   // [S, O]
    float*       __restrict__ out)    // [B, O]
{
    __shared__ float          Wt[O * D];         // 16 KB: plane o at Wt[o*1024+d]
    __shared__ unsigned short list[WAVES][SEG];  // 4 KB: per-wave match lists

    const int t    = threadIdx.x;
    const int lane = t & 63;
    const int wave = t >> 6;
    const int s    = blockIdx.x >> 4;         // 16 consecutive blocks share s
    const int c    = blockIdx.x & 15;
    const int q    = lane >> 4;               // output index this lane stores

    // ---- 1. Scan my 256-row sid segment, ballot-compact matches into the
    //         wave-private list (wave-coherent LDS: no barrier needed). ----
    const int seg = c * CHUNK + wave * SEG;
    int cnt = 0;
    #pragma unroll
    for (int r = 0; r < 4; ++r) {
        const int i = seg + r * 64 + lane;                 // coalesced 256B
        const bool m = (sid[i] == s);
        const unsigned long long mask = __ballot(m);
        const int rank = __popcll(mask & ((1ull << lane) - 1ull));
        if (m) list[wave][cnt + rank] = (unsigned short)i;
        cnt += __popcll(mask);                             // lane-uniform
    }

    // ---- 2. First x-row prefetch + bias, BEFORE the barrier: x stream
    //         starts under the W-stage latency. ----
    const float bb = bias[(s << 2) + q];
    float4 xb[4];
    int rowC = 0;
    if (cnt) {
        rowC = __builtin_amdgcn_readfirstlane((int)list[wave][0]);
        const float4* xr = (const float4*)(x + ((size_t)rowC << 10));
        #pragma unroll
        for (int j = 0; j < 4; ++j) xb[j] = xr[64 * j + lane];
    }

    // ---- 3. Stage W[s]^T into LDS: 512 threads x 2 float4 (coalesced
    //         reads; scalar writes bank = d%32, 2 lanes/bank = free). ----
    {
        const float4* Wp = (const float4*)(W + (size_t)s * (D * O));
        #pragma unroll
        for (int r = 0; r < 2; ++r) {
            const int d = r * 512 + t;
            const float4 w4 = Wp[d];          // W[s][d][0..3]
            Wt[0 * D + d] = w4.x;
            Wt[1 * D + d] = w4.y;
            Wt[2 * D + d] = w4.z;
            Wt[3 * D + d] = w4.w;
        }
    }

    __syncthreads();                          // Wt visible to all waves
    if (cnt == 0) return;

    const float4* Wt4 = (const float4*)Wt;    // plane o at float4 index o*256

    // ---- 4. Stream matched rows (R5's proven 64-reg single-xb shape):
    //         FMA current row, then prefetch next into the same regs. ----
    #pragma unroll 1
    for (int k = 0; k < cnt; ++k) {
        const bool more = (k + 1 < cnt);
        const int rowN = more
            ? __builtin_amdgcn_readfirstlane((int)list[wave][k + 1]) : rowC;

        float a0 = 0.f, a1 = 0.f, a2 = 0.f, a3 = 0.f;
        #pragma unroll
        for (int j = 0; j < 4; ++j) {
            const float4 xv = xb[j];
            const float4 w0 = Wt4[0 * 256 + 64 * j + lane];  // 16B lane stride
            const float4 w1 = Wt4[1 * 256 + 64 * j + lane];
            const float4 w2 = Wt4[2 * 256 + 64 * j + lane];
            const float4 w3 = Wt4[3 * 256 + 64 * j + lane];
            a0 += xv.x * w0.x; a1 += xv.x * w1.x;
            a2 += xv.x * w2.x; a3 += xv.x * w3.x;
            a0 += xv.y * w0.y; a1 += xv.y * w1.y;
            a2 += xv.y * w2.y; a3 += xv.y * w3.y;
            a0 += xv.z * w0.z; a1 += xv.z * w1.z;
            a2 += xv.z * w2.z; a3 += xv.z * w3.z;
            a0 += xv.w * w0.w; a1 += xv.w * w1.w;
            a2 += xv.w * w2.w; a3 += xv.w * w3.w;
        }

        if (more) {                            // prefetch next row's x
            const float4* xr = (const float4*)(x + ((size_t)rowN << 10));
            #pragma unroll
            for (int j = 0; j < 4; ++j) xb[j] = xr[64 * j + lane];
        }

        // 12-op reduce: xor{16,32} on 4 accs -> per-(lane%16) partials;
        // lane picks q = lane>>4; xor{1,2,4,8} sums the 16 residues.
        #pragma unroll
        for (int m = 16; m <= 32; m <<= 1) {
            a0 += __shfl_xor(a0, m, 64);
            a1 += __shfl_xor(a1, m, 64);
            a2 += __shfl_xor(a2, m, 64);
            a3 += __shfl_xor(a3, m, 64);
        }
        float v = (q == 0) ? a0 : (q == 1) ? a1 : (q == 2) ? a2 : a3;
        #pragma unroll
        for (int m = 1; m <= 8; m <<= 1)
            v += __shfl_xor(v, m, 64);

        if ((lane & 15) == 0)                 // lanes 0,16,32,48 -> o = 0..3
            out[((size_t)rowC << 2) + q] = v + bb;

        rowC = rowN;
    }
}

extern "C" void kernel_launch(void* const* d_in, const int* in_sizes, int n_in,
                              void* d_out, int out_size, void* d_ws, size_t ws_size,
                              hipStream_t stream) {
    const float* x    = (const float*)d_in[0];   // [B, D]
    const int*   sid  = (const int*)d_in[1];     // [B]
    const float* W    = (const float*)d_in[2];   // [S, D, O]
    const float* bias = (const float*)d_in[3];   // [S, O]
    float* out = (float*)d_out;                  // [B, O]

    main_kernel<<<MAIN_BLOCKS, 512, 0, stream>>>(x, sid, W, bias, out);
}

// Round 8
// 190.206 us; speedup vs baseline: 1.0841x; 1.0650x over previous
//
#include <hip/hip_runtime.h>

// Problem constants (match reference file)
constexpr int B = 32768;
constexpr int D = 1024;
constexpr int S = 64;
constexpr int O = 4;

// ---------------------------------------------------------------------------
// R8 = R5 (best: 200.5us) with EXACTLY ONE change: the x stream is loaded
// non-temporally (nt bit).
//
// Evidence chain: R7 (halved prologue traffic, pre-barrier prefetch) changed
// nothing -> steady loop limited.  R5's custom portion ~45us for a mandatory
// 128MiB x read = 2.86 TB/s effective read BW, while the harness's pure-WRITE
// fills sustain 87% of peak.  In-flight bytes are ample (32 waves/CU x 4KB),
// so the cap is per-CU read-path line tracking (L1/MSHR): ~4KB of lines in
// flight per CU at ~900cy HBM latency ~= 2.9 TB/s chip-wide -- exactly where
// we sit.  Writes need no MSHRs, hence the fill/read asymmetry.  nt marks
// the once-streamed x as no-allocate/streaming in L1, relieving that
// pressure.  No caching downside: x is read once per iteration and the 512MB
// poison fills evict it from L3 between iterations regardless.
//
// (HIP float4 is a struct, which __builtin_nontemporal_load rejects; the hot
// path uses a clang ext_vector f32x4 instead -- .x/.y/.z/.w still work.)
// ---------------------------------------------------------------------------

constexpr int CHUNKS      = 32;             // chunks per subject
constexpr int CHUNK       = B / CHUNKS;     // 1024 rows per block
constexpr int SEG         = CHUNK / 4;      // 256 rows per wave
constexpr int MAIN_BLOCKS = S * CHUNKS;     // 2048 blocks

typedef float f4 __attribute__((ext_vector_type(4)));

__global__ __launch_bounds__(256) void main_kernel(
    const float* __restrict__ x,      // [B, D]
    const int*   __restrict__ sid,    // [B]
    const float* __restrict__ W,      // [S, D, O]
    const float* __restrict__ bias,   // [S, O]
    float*       __restrict__ out)    // [B, O]
{
    __shared__ float Wt[O * D];               // 16 KB: plane o at Wt[o*1024 + d]
    __shared__ int   list[4][SEG];            // 4 KB: per-wave match lists

    const int t    = threadIdx.x;
    const int lane = t & 63;
    const int wave = t >> 6;
    const int s    = blockIdx.x >> 5;         // 32 consecutive blocks share s
    const int c    = blockIdx.x & 31;
    const int q    = lane >> 4;               // output index this lane stores

    // ---- 1. Stage W[s]^T into LDS (coalesced float4 reads, conflict-free
    //         scalar writes: bank = d%32 = t%32, 2 lanes/bank = free). ----
    {
        const float4* Wp = (const float4*)(W + (size_t)s * (D * O));
        #pragma unroll
        for (int r = 0; r < 4; ++r) {
            const int d = r * 256 + t;
            const float4 w4 = Wp[d];          // W[s][d][0..3]
            Wt[0 * D + d] = w4.x;
            Wt[1 * D + d] = w4.y;
            Wt[2 * D + d] = w4.z;
            Wt[3 * D + d] = w4.w;
        }
    }

    // ---- 2. Scan my 256-row sid segment, ballot-compact matches into the
    //         wave-private list. ----
    const int seg = c * CHUNK + wave * SEG;
    int cnt = 0;
    #pragma unroll
    for (int r = 0; r < 4; ++r) {
        const int i = seg + r * 64 + lane;                 // coalesced 256B
        const bool m = (sid[i] == s);
        const unsigned long long mask = __ballot(m);
        const int rank = __popcll(mask & ((1ull << lane) - 1ull));
        if (m) list[wave][cnt + rank] = i;
        cnt += __popcll(mask);                             // lane-uniform
    }

    __syncthreads();                          // Wt visible to all waves
    if (cnt == 0) return;                     // no barriers after this point

    const float bb  = bias[(s << 2) + q];
    const f4*   Wt4 = (const f4*)Wt;          // plane o at f4 index o*256

    // ---- 3. Stream matched rows; x loads are NON-TEMPORAL (streamed once).
    int rowC = __builtin_amdgcn_readfirstlane(list[wave][0]);
    f4 xb[4];
    {
        const f4* xr = (const f4*)(x + ((size_t)rowC << 10));
        #pragma unroll
        for (int j = 0; j < 4; ++j)
            xb[j] = __builtin_nontemporal_load(xr + 64 * j + lane);
    }

    #pragma unroll 1
    for (int k = 0; k < cnt; ++k) {
        const bool more = (k + 1 < cnt);
        const int rowN = more
            ? __builtin_amdgcn_readfirstlane(list[wave][k + 1]) : rowC;

        float a0 = 0.f, a1 = 0.f, a2 = 0.f, a3 = 0.f;
        #pragma unroll
        for (int j = 0; j < 4; ++j) {
            const f4 xv = xb[j];
            const f4 w0 = Wt4[0 * 256 + 64 * j + lane];  // 16B lane stride,
            const f4 w1 = Wt4[1 * 256 + 64 * j + lane];  // conflict-free
            const f4 w2 = Wt4[2 * 256 + 64 * j + lane];
            const f4 w3 = Wt4[3 * 256 + 64 * j + lane];
            a0 += xv.x * w0.x; a1 += xv.x * w1.x;
            a2 += xv.x * w2.x; a3 += xv.x * w3.x;
            a0 += xv.y * w0.y; a1 += xv.y * w1.y;
            a2 += xv.y * w2.y; a3 += xv.y * w3.y;
            a0 += xv.z * w0.z; a1 += xv.z * w1.z;
            a2 += xv.z * w2.z; a3 += xv.z * w3.z;
            a0 += xv.w * w0.w; a1 += xv.w * w1.w;
            a2 += xv.w * w2.w; a3 += xv.w * w3.w;
        }

        if (more) {                            // prefetch next row's x (nt)
            const f4* xr = (const f4*)(x + ((size_t)rowN << 10));
            #pragma unroll
            for (int j = 0; j < 4; ++j)
                xb[j] = __builtin_nontemporal_load(xr + 64 * j + lane);
        }

        // 12-op reduce: xor{16,32} on 4 accs -> per-(lane%16) partials;
        // lane picks q = lane>>4; xor{1,2,4,8} sums the 16 residues.
        #pragma unroll
        for (int m = 16; m <= 32; m <<= 1) {
            a0 += __shfl_xor(a0, m, 64);
            a1 += __shfl_xor(a1, m, 64);
            a2 += __shfl_xor(a2, m, 64);
            a3 += __shfl_xor(a3, m, 64);
        }
        float v = (q == 0) ? a0 : (q == 1) ? a1 : (q == 2) ? a2 : a3;
        #pragma unroll
        for (int m = 1; m <= 8; m <<= 1)
            v += __shfl_xor(v, m, 64);

        if ((lane & 15) == 0)                 // lanes 0,16,32,48 -> o = 0..3
            out[((size_t)rowC << 2) + q] = v + bb;

        rowC = rowN;
    }
}

extern "C" void kernel_launch(void* const* d_in, const int* in_sizes, int n_in,
                              void* d_out, int out_size, void* d_ws, size_t ws_size,
                              hipStream_t stream) {
    const float* x    = (const float*)d_in[0];   // [B, D]
    const int*   sid  = (const int*)d_in[1];     // [B]
    const float* W    = (const float*)d_in[2];   // [S, D, O]
    const float* bias = (const float*)d_in[3];   // [S, O]
    float* out = (float*)d_out;                  // [B, O]

    main_kernel<<<MAIN_BLOCKS, 256, 0, stream>>>(x, sid, W, bias, out);
}